// Round 1
// baseline (3635.404 us; speedup 1.0000x reference)
//
#include <hip/hip_runtime.h>
#include <hip/hip_bf16.h>
#include <stdint.h>

// Problem constants (B=4, S=2048 -> T=8192 tokens)
#define T_TOK 8192
#define Hdim  2048
#define Fdim  4096
#define Edim  8
#define NCHUNK 4
#define FC (Fdim / NCHUNK)   // 1024 F-columns per chunk

// GEMM tile config
#define BM 128
#define BN 128
#define BK 32
#define LDA 36   // padded LDS leading dim (elems) for A tiles (rows 72B, 8B-aligned)
#define LDB 36   // padded LDS leading dim for transposed B tiles

// Workspace layout (bytes)
#define WS_LIST_OFF  256
#define WS_WSLOT_OFF (WS_LIST_OFF + (size_t)Edim * T_TOK * 4)          // 262400
#define WS_XBF_OFF   (WS_WSLOT_OFF + (size_t)2 * T_TOK * 4)            // 327936
#define WS_G_OFF     (WS_XBF_OFF + (size_t)T_TOK * Hdim * 2)           // 33882368
// total need: WS_G_OFF + 2*T_TOK*FC*2 = 67,436,800 bytes

typedef short  bf16x8 __attribute__((ext_vector_type(8)));
typedef float  f32x4  __attribute__((ext_vector_type(4)));

__device__ __forceinline__ unsigned short bf_rne(float f) {
  uint32_t u = __float_as_uint(f);
  u += 0x7FFFu + ((u >> 16) & 1u);
  return (unsigned short)(u >> 16);
}

__device__ __forceinline__ bf16x8 ld_frag(const unsigned short* p) {
  union { uint2 q[2]; bf16x8 v; } u;
  u.q[0] = *(const uint2*)(p);
  u.q[1] = *(const uint2*)(p + 4);
  return u.v;
}

// ---------------- x fp32 -> bf16 ----------------
__global__ void cvt_x_kernel(const float* __restrict__ X, unsigned short* __restrict__ Xbf) {
  const int n4 = T_TOK * Hdim / 4;
  for (int i = blockIdx.x * blockDim.x + threadIdx.x; i < n4; i += gridDim.x * blockDim.x) {
    float4 v = ((const float4*)X)[i];
    ushort4 o;
    o.x = bf_rne(v.x); o.y = bf_rne(v.y); o.z = bf_rne(v.z); o.w = bf_rne(v.w);
    ((ushort4*)Xbf)[i] = o;
  }
}

// ---------------- router: logits (fp64 acc), top-2, scatter ----------------
__global__ void router_kernel(const float* __restrict__ X, const float* __restrict__ gw,
                              float* __restrict__ logits, int* __restrict__ counts,
                              int* __restrict__ list, float* __restrict__ wslot) {
  const int t = blockIdx.x;
  const int tid = threadIdx.x;
  const float* x = X + (size_t)t * Hdim;

  double acc[Edim];
#pragma unroll
  for (int e = 0; e < Edim; e++) acc[e] = 0.0;

  for (int h = tid; h < Hdim; h += 256) {
    float xv = x[h];
    const float* g = gw + (size_t)h * Edim;
#pragma unroll
    for (int e = 0; e < Edim; e++) acc[e] += (double)xv * (double)g[e];
  }

  __shared__ double sm[256 * Edim];
#pragma unroll
  for (int e = 0; e < Edim; e++) sm[tid * Edim + e] = acc[e];
  __syncthreads();
  for (int s = 128; s > 0; s >>= 1) {
    if (tid < s) {
#pragma unroll
      for (int e = 0; e < Edim; e++) sm[tid * Edim + e] += sm[(tid + s) * Edim + e];
    }
    __syncthreads();
  }

  if (tid == 0) {
    float l[Edim];
#pragma unroll
    for (int e = 0; e < Edim; e++) { l[e] = (float)sm[e]; logits[(size_t)t * Edim + e] = l[e]; }
    // top-2, first occurrence wins ties (matches jax.lax.top_k)
    int i1 = 0; float m1 = l[0];
#pragma unroll
    for (int e = 1; e < Edim; e++) if (l[e] > m1) { m1 = l[e]; i1 = e; }
    int i2 = -1; float m2 = -3.0e38f;
#pragma unroll
    for (int e = 0; e < Edim; e++) {
      if (e == i1) continue;
      if (i2 < 0 || l[e] > m2) { m2 = l[e]; i2 = e; }
    }
    float eb = expf(m2 - m1);
    float wa = 1.0f / (1.0f + eb);
    float wb = eb / (1.0f + eb);
    int p1 = atomicAdd(&counts[i1], 1);
    list[i1 * T_TOK + p1] = 2 * t;
    wslot[2 * t] = wa;
    int p2 = atomicAdd(&counts[i2], 1);
    list[i2 * T_TOK + p2] = 2 * t + 1;
    wslot[2 * t + 1] = wb;
  }
}

// ---------------- up: G = silu(X@W1) * (X@W3)  (per-expert segment, one F-chunk) ----------------
__global__ __launch_bounds__(256, 2) void up_kernel(
    const unsigned short* __restrict__ Xbf, const float* __restrict__ w1,
    const float* __restrict__ w3, const int* __restrict__ counts,
    const int* __restrict__ list, unsigned short* __restrict__ G, int f0) {
  const int e = blockIdx.z;
  const int cnt = counts[e];
  const int m0 = blockIdx.y * BM;
  if (m0 >= cnt) return;
  const int n0 = blockIdx.x * BN;   // within chunk [0, FC)

  __shared__ unsigned short sA[BM * LDA];
  __shared__ unsigned short sB1[BN * LDB];
  __shared__ unsigned short sB3[BN * LDB];
  __shared__ int sRow[BM];

  const int tid = threadIdx.x;
  if (tid < BM) {
    int r = m0 + tid;
    sRow[tid] = (r < cnt) ? list[e * T_TOK + r] : 0;
  }

  f32x4 acc1[4][4] = {};
  f32x4 acc3[4][4] = {};

  const int wave = tid >> 6, lane = tid & 63;
  const int wr = (wave >> 1) * 64, wc = (wave & 1) * 64;
  const int quad = lane >> 4, l16 = lane & 15;

  const float* B1p = w1 + (size_t)e * Hdim * Fdim + f0 + n0;
  const float* B3p = w3 + (size_t)e * Hdim * Fdim + f0 + n0;
  __syncthreads();

  for (int k0 = 0; k0 < Hdim; k0 += BK) {
    // stage A (gathered bf16 rows)
#pragma unroll
    for (int i = 0; i < 4; i++) {
      int idx = tid + i * 256;          // 0..1023
      int row = idx >> 3;               // 0..127
      int kc  = (idx & 7) * 4;          // 0..28
      int tok = sRow[row] >> 1;
      ushort4 v = *(const ushort4*)(Xbf + (size_t)tok * Hdim + k0 + kc);
      *(ushort4*)&sA[row * LDA + kc] = v;
    }
    // stage B1/B3 (fp32 -> bf16, transpose into LDS)
#pragma unroll
    for (int i = 0; i < 4; i++) {
      int idx = tid + i * 256;          // 0..1023
      int k  = idx >> 5;                // 0..31
      int nc = (idx & 31) * 4;          // 0..124
      const float4 v1 = *(const float4*)(B1p + (size_t)(k0 + k) * Fdim + nc);
      const float4 v3 = *(const float4*)(B3p + (size_t)(k0 + k) * Fdim + nc);
      sB1[(nc + 0) * LDB + k] = bf_rne(v1.x);
      sB1[(nc + 1) * LDB + k] = bf_rne(v1.y);
      sB1[(nc + 2) * LDB + k] = bf_rne(v1.z);
      sB1[(nc + 3) * LDB + k] = bf_rne(v1.w);
      sB3[(nc + 0) * LDB + k] = bf_rne(v3.x);
      sB3[(nc + 1) * LDB + k] = bf_rne(v3.y);
      sB3[(nc + 2) * LDB + k] = bf_rne(v3.z);
      sB3[(nc + 3) * LDB + k] = bf_rne(v3.w);
    }
    __syncthreads();

    bf16x8 af[4], b1f[4], b3f[4];
#pragma unroll
    for (int mt = 0; mt < 4; mt++)
      af[mt] = ld_frag(&sA[(wr + mt * 16 + l16) * LDA + quad * 8]);
#pragma unroll
    for (int nt = 0; nt < 4; nt++) {
      b1f[nt] = ld_frag(&sB1[(wc + nt * 16 + l16) * LDB + quad * 8]);
      b3f[nt] = ld_frag(&sB3[(wc + nt * 16 + l16) * LDB + quad * 8]);
    }
#pragma unroll
    for (int mt = 0; mt < 4; mt++)
#pragma unroll
      for (int nt = 0; nt < 4; nt++) {
        acc1[mt][nt] = __builtin_amdgcn_mfma_f32_16x16x32_bf16(af[mt], b1f[nt], acc1[mt][nt], 0, 0, 0);
        acc3[mt][nt] = __builtin_amdgcn_mfma_f32_16x16x32_bf16(af[mt], b3f[nt], acc3[mt][nt], 0, 0, 0);
      }
    __syncthreads();
  }

  // epilogue: G[id][col] = bf16( silu(y1) * y3 )
#pragma unroll
  for (int mt = 0; mt < 4; mt++) {
#pragma unroll
    for (int r = 0; r < 4; r++) {
      int lr = wr + mt * 16 + quad * 4 + r;
      bool ok = (m0 + lr) < cnt;
      int id = sRow[lr];
      size_t gbase = (size_t)id * FC;
#pragma unroll
      for (int nt = 0; nt < 4; nt++) {
        float y1 = acc1[mt][nt][r];
        float y3 = acc3[mt][nt][r];
        float s = y1 / (1.0f + __expf(-y1));
        float g = s * y3;
        int col = n0 + wc + nt * 16 + l16;
        if (ok) G[gbase + col] = bf_rne(g);
      }
    }
  }
}

// ---------------- down: out += w_tok * (G @ W2)  (atomic combine) ----------------
__global__ __launch_bounds__(256, 2) void down_kernel(
    const unsigned short* __restrict__ G, const float* __restrict__ w2,
    const int* __restrict__ counts, const int* __restrict__ list,
    const float* __restrict__ wslot, float* __restrict__ out, int f0) {
  const int e = blockIdx.z;
  const int cnt = counts[e];
  const int m0 = blockIdx.y * BM;
  if (m0 >= cnt) return;
  const int n0 = blockIdx.x * BN;   // over H

  __shared__ unsigned short sA[BM * LDA];
  __shared__ unsigned short sB[BN * LDB];
  __shared__ int   sId[BM];
  __shared__ float sW[BM];

  const int tid = threadIdx.x;
  if (tid < BM) {
    int r = m0 + tid;
    int id = (r < cnt) ? list[e * T_TOK + r] : 0;
    sId[tid] = id;
    sW[tid] = (r < cnt) ? wslot[id] : 0.0f;
  }

  f32x4 acc[4][4] = {};

  const int wave = tid >> 6, lane = tid & 63;
  const int wr = (wave >> 1) * 64, wc = (wave & 1) * 64;
  const int quad = lane >> 4, l16 = lane & 15;

  const float* Bp = w2 + (size_t)e * Fdim * Hdim + n0;
  __syncthreads();

  for (int k0 = 0; k0 < FC; k0 += BK) {
    // stage A from G (bf16)
#pragma unroll
    for (int i = 0; i < 4; i++) {
      int idx = tid + i * 256;
      int row = idx >> 3;
      int kc  = (idx & 7) * 4;
      int id = sId[row];
      ushort4 v = *(const ushort4*)(G + (size_t)id * FC + k0 + kc);
      *(ushort4*)&sA[row * LDA + kc] = v;
    }
    // stage B from W2 (fp32 -> bf16 transpose)
#pragma unroll
    for (int i = 0; i < 4; i++) {
      int idx = tid + i * 256;
      int k  = idx >> 5;
      int nc = (idx & 31) * 4;
      const float4 v = *(const float4*)(Bp + (size_t)(f0 + k0 + k) * Hdim + nc);
      sB[(nc + 0) * LDB + k] = bf_rne(v.x);
      sB[(nc + 1) * LDB + k] = bf_rne(v.y);
      sB[(nc + 2) * LDB + k] = bf_rne(v.z);
      sB[(nc + 3) * LDB + k] = bf_rne(v.w);
    }
    __syncthreads();

    bf16x8 af[4], bf[4];
#pragma unroll
    for (int mt = 0; mt < 4; mt++)
      af[mt] = ld_frag(&sA[(wr + mt * 16 + l16) * LDA + quad * 8]);
#pragma unroll
    for (int nt = 0; nt < 4; nt++)
      bf[nt] = ld_frag(&sB[(wc + nt * 16 + l16) * LDB + quad * 8]);
#pragma unroll
    for (int mt = 0; mt < 4; mt++)
#pragma unroll
      for (int nt = 0; nt < 4; nt++)
        acc[mt][nt] = __builtin_amdgcn_mfma_f32_16x16x32_bf16(af[mt], bf[nt], acc[mt][nt], 0, 0, 0);
    __syncthreads();
  }

#pragma unroll
  for (int mt = 0; mt < 4; mt++) {
#pragma unroll
    for (int r = 0; r < 4; r++) {
      int lr = wr + mt * 16 + quad * 4 + r;
      if ((m0 + lr) < cnt) {
        int tok = sId[lr] >> 1;
        float wgt = sW[lr];
        float* op = out + (size_t)tok * Hdim + n0;
#pragma unroll
        for (int nt = 0; nt < 4; nt++) {
          int col = wc + nt * 16 + l16;
          atomicAdd(op + col, acc[mt][nt][r] * wgt);
        }
      }
    }
  }
}

extern "C" void kernel_launch(void* const* d_in, const int* in_sizes, int n_in,
                              void* d_out, int out_size, void* d_ws, size_t ws_size,
                              hipStream_t stream) {
  const float* X  = (const float*)d_in[0];
  const float* gw = (const float*)d_in[1];
  const float* w1 = (const float*)d_in[2];
  const float* w3 = (const float*)d_in[3];
  const float* w2 = (const float*)d_in[4];
  float* out = (float*)d_out;
  float* logits = out + (size_t)T_TOK * Hdim;

  char* ws = (char*)d_ws;
  int* counts = (int*)ws;
  int* list = (int*)(ws + WS_LIST_OFF);
  float* wslot = (float*)(ws + WS_WSLOT_OFF);
  unsigned short* Xbf = (unsigned short*)(ws + WS_XBF_OFF);
  unsigned short* G = (unsigned short*)(ws + WS_G_OFF);

  hipMemsetAsync(counts, 0, 256, stream);
  hipMemsetAsync(out, 0, (size_t)T_TOK * Hdim * sizeof(float), stream);

  cvt_x_kernel<<<2048, 256, 0, stream>>>(X, Xbf);
  router_kernel<<<T_TOK, 256, 0, stream>>>(X, gw, logits, counts, list, wslot);

  for (int c = 0; c < NCHUNK; c++) {
    int f0 = c * FC;
    up_kernel<<<dim3(FC / BN, 64, Edim), 256, 0, stream>>>(Xbf, w1, w3, counts, list, G, f0);
    down_kernel<<<dim3(Hdim / BN, 64, Edim), 256, 0, stream>>>(G, w2, counts, list, wslot, out, f0);
  }
}